// Round 2
// baseline (713.702 us; speedup 1.0000x reference)
//
#include <hip/hip_runtime.h>
#include <stdint.h>

typedef __attribute__((ext_vector_type(8))) short short8;
typedef __attribute__((ext_vector_type(4))) float f32x4;

#define MFMA16(a,b,c) __builtin_amdgcn_mfma_f32_16x16x32_bf16((a),(b),(c),0,0,0)

__device__ __forceinline__ unsigned short f2bf(float f){
  unsigned u = __builtin_bit_cast(unsigned, f);
  u += 0x7fffu + ((u >> 16) & 1u);
  return (unsigned short)(u >> 16);
}

static constexpr int HW_ = 50176;   // 224*224

// ---------------- weights fp32 -> bf16 ----------------
__global__ void k_convw(const float* __restrict__ Wq, const float* __restrict__ Wk,
                        const float* __restrict__ Wv, const float* __restrict__ Wo,
                        unsigned short* __restrict__ Wqkv, unsigned short* __restrict__ Wob){
  int i = blockIdx.x * 256 + threadIdx.x;           // grid = 256 blocks -> i < 65536
  Wqkv[i]           = f2bf(Wq[i]);
  Wqkv[65536 + i]   = f2bf(Wk[i]);
  Wqkv[131072 + i]  = f2bf(Wv[i]);
  Wob[i]            = f2bf(Wo[i]);
}

// ---------------- x (B,C,HW) f32 -> xbT (B,HW,C) bf16 ----------------
// tile: [64 px][72 pitch], channel chunks XOR-swizzled by (px>>3)&7
__global__ __launch_bounds__(256) void k_xpose(const float* __restrict__ x, unsigned short* __restrict__ xbT){
  int bid = blockIdx.x;
  int pt = bid % 784; int rest = bid / 784;
  int ct = rest & 3;  int b = rest >> 2;
  __shared__ unsigned short tile[64 * 72];
  int t = threadIdx.x;
#pragma unroll
  for (int it = 0; it < 4; ++it){
    int idx = it * 256 + t;
    int c = idx >> 4, s = idx & 15;          // c: 0..63 channel, s: 0..15 (4-px group)
    float4 v = *(const float4*)(x + ((size_t)(b * 256 + ct * 64 + c)) * HW_ + pt * 64 + s * 4);
    float vv[4] = {v.x, v.y, v.z, v.w};
#pragma unroll
    for (int j = 0; j < 4; ++j){
      int px = s * 4 + j;
      int g = (px >> 3) & 7;
      tile[px * 72 + (((c >> 3) ^ g) << 3) + (c & 7)] = f2bf(vv[j]);
    }
  }
  __syncthreads();
#pragma unroll
  for (int it = 0; it < 2; ++it){
    int idx = it * 256 + t;
    int p = idx >> 3, s = idx & 7;           // p: 0..63 px, s: 0..7 channel chunk
    int g = (p >> 3) & 7;
    short8 v = *(const short8*)&tile[p * 72 + ((s ^ g) << 3)];
    *(short8*)(xbT + ((size_t)b * HW_ + pt * 64 + p) * 256 + ct * 64 + s * 8) = v;
  }
}

// ---------------- GEMM: qkvT[b][p][o] = sum_c Wqkv[o][c] * xbT[b][p][c] ----------------
// 128x128 tile, BK=64, 4 waves (2x2), 16x16x32 bf16 MFMA, XOR-swizzled LDS [row][64k]
__global__ __launch_bounds__(256) void k_gemm_qkv(const unsigned short* __restrict__ Wb,
                                                  const unsigned short* __restrict__ xbT,
                                                  unsigned short* __restrict__ qkvT){
  int bid = blockIdx.x;
  int mt = bid % 6; int rest = bid / 6;
  int nt = rest % 392; int b = rest / 392;
  const unsigned short* Asrc = Wb + mt * 128 * 256;
  const unsigned short* Bsrc = xbT + ((size_t)b * HW_ + (size_t)nt * 128) * 256;

  __shared__ unsigned short lds[17408];   // staging A[0..8191] B[8192..16383]; epilogue Ct[128][136]
  unsigned short* Alds = lds;
  unsigned short* Blds = lds + 8192;

  int tid = threadIdx.x;
  int lane = tid & 63;
  int wave = tid >> 6;
  int wm = wave >> 1, wn = wave & 1;

  f32x4 acc[4][4] = {};

  for (int k0 = 0; k0 < 256; k0 += 64){
    short8 ra[4], rb[4];
#pragma unroll
    for (int c = 0; c < 4; ++c){
      int q = c * 256 + tid;               // 0..1023 chunk id (16B each)
      int r = q >> 3, sl = q & 7;
      ra[c] = *(const short8*)(Asrc + r * 256 + k0 + sl * 8);
      rb[c] = *(const short8*)(Bsrc + r * 256 + k0 + sl * 8);
    }
    __syncthreads();                        // prev compute done before overwrite
#pragma unroll
    for (int c = 0; c < 4; ++c){
      int q = c * 256 + tid;
      int r = q >> 3, sl = q & 7;
      int ps = sl ^ (r & 7);                // XOR swizzle (128B rows)
      *(short8*)(Alds + r * 64 + ps * 8) = ra[c];
      *(short8*)(Blds + r * 64 + ps * 8) = rb[c];
    }
    __syncthreads();
#pragma unroll
    for (int kk = 0; kk < 2; ++kk){
      short8 af[4], bfv[4];
#pragma unroll
      for (int i = 0; i < 4; ++i){
        int row = wm * 64 + i * 16 + (lane & 15);
        int ps = (kk * 4 + (lane >> 4)) ^ (row & 7);
        af[i] = *(const short8*)(Alds + row * 64 + ps * 8);
      }
#pragma unroll
      for (int j = 0; j < 4; ++j){
        int row = wn * 64 + j * 16 + (lane & 15);
        int ps = (kk * 4 + (lane >> 4)) ^ (row & 7);
        bfv[j] = *(const short8*)(Blds + row * 64 + ps * 8);
      }
#pragma unroll
      for (int i = 0; i < 4; ++i)
#pragma unroll
        for (int j = 0; j < 4; ++j)
          acc[i][j] = MFMA16(af[i], bfv[j], acc[i][j]);
    }
  }
  __syncthreads();
  // transpose in LDS -> coalesced pixel-major store
#pragma unroll
  for (int i = 0; i < 4; ++i)
#pragma unroll
    for (int j = 0; j < 4; ++j){
      int o_loc = wm * 64 + i * 16 + (lane >> 4) * 4;
      int n_loc = wn * 64 + j * 16 + (lane & 15);
      unsigned long long pk =
          (unsigned long long)f2bf(acc[i][j][0]) |
          ((unsigned long long)f2bf(acc[i][j][1]) << 16) |
          ((unsigned long long)f2bf(acc[i][j][2]) << 32) |
          ((unsigned long long)f2bf(acc[i][j][3]) << 48);
      *(unsigned long long*)(lds + n_loc * 136 + o_loc) = pk;
    }
  __syncthreads();
  size_t outb = (size_t)b * HW_ + (size_t)nt * 128;
  int n_loc = tid >> 1, half = tid & 1;
#pragma unroll
  for (int cc = 0; cc < 8; ++cc){
    short8 v = *(const short8*)(lds + n_loc * 136 + half * 64 + cc * 8);
    *(short8*)(qkvT + (outb + n_loc) * 768 + mt * 128 + half * 64 + cc * 8) = v;
  }
}

// ---------------- window attention, 1 wave = 1 (b,window,head) ----------------
__global__ __launch_bounds__(64) void k_attn(const unsigned short* __restrict__ qkvT,
                                             unsigned short* __restrict__ attnT){
  int bid = blockIdx.x;
  int h = bid & 7;
  int win = (bid >> 3) & 1023;
  int b = bid >> 13;
  int wh = win >> 5, ww = win & 31;
  int lane = threadIdx.x;

  __shared__ unsigned short sVT[2048];  // [32 d][64 px] pitch 64 elems, XOR swz on d
  __shared__ unsigned short sP[4096];   // [64 q][64 kp] pitch 64 elems, XOR swz on q

  const size_t rowbase = (size_t)b * HW_;
  auto pxaddr = [&](int px){ return rowbase + (size_t)((wh*7 + px/7)*224 + ww*7 + px%7); };

  { // stage V -> V^T in LDS (zero pad cols 49..63 to avoid NaN garbage)
    int px = lane < 49 ? lane : 48;
    const unsigned short* src = qkvT + pxaddr(px) * 768 + 512 + h * 32;
    short8 v0 = *(const short8*)(src);
    short8 v1 = *(const short8*)(src + 8);
    short8 v2 = *(const short8*)(src + 16);
    short8 v3 = *(const short8*)(src + 24);
    bool val = (lane < 49);
    unsigned short e[32];
#pragma unroll
    for (int d = 0; d < 8; ++d){
      e[d]    = (unsigned short)v0[d];  e[8+d]  = (unsigned short)v1[d];
      e[16+d] = (unsigned short)v2[d];  e[24+d] = (unsigned short)v3[d];
    }
#pragma unroll
    for (int d = 0; d < 32; ++d){
      int bo = (d * 128 + lane * 2) ^ ((d & 7) << 4);
      sVT[bo >> 1] = val ? e[d] : (unsigned short)0;
    }
  }

  // S^T = K * Q^T  (A = K rows k', B = Q rows q) -> D[k'][q]
  short8 kf[4], qf[4];
#pragma unroll
  for (int i = 0; i < 4; ++i){
    int px = i * 16 + (lane & 15); if (px > 48) px = 48;
    const unsigned short* base = qkvT + pxaddr(px) * 768 + h * 32 + (lane >> 4) * 8;
    qf[i] = *(const short8*)(base);
    kf[i] = *(const short8*)(base + 256);
  }
  f32x4 s[4][4] = {};
#pragma unroll
  for (int mi = 0; mi < 4; ++mi)
#pragma unroll
    for (int ni = 0; ni < 4; ++ni)
      s[mi][ni] = MFMA16(kf[mi], qf[ni], s[mi][ni]);

  // softmax over k' (rows of S^T) per q column; write P[q][k'] bf16 to LDS
  const float cexp = 0.25504437f;   // log2(e)/sqrt(32)
#pragma unroll
  for (int ni = 0; ni < 4; ++ni){
    float m = -3.0e38f;
#pragma unroll
    for (int mi = 0; mi < 4; ++mi)
#pragma unroll
      for (int r = 0; r < 4; ++r){
        int kp = mi * 16 + ((lane >> 4) * 4) + r;
        if (kp < 49) m = fmaxf(m, s[mi][ni][r]);
      }
    m = fmaxf(m, __shfl_xor(m, 16));
    m = fmaxf(m, __shfl_xor(m, 32));
    float sum = 0.f;
    float pv[4][4];
#pragma unroll
    for (int mi = 0; mi < 4; ++mi)
#pragma unroll
      for (int r = 0; r < 4; ++r){
        int kp = mi * 16 + ((lane >> 4) * 4) + r;
        float e2 = (kp < 49) ? exp2f((s[mi][ni][r] - m) * cexp) : 0.f;
        pv[mi][r] = e2; sum += e2;
      }
    sum += __shfl_xor(sum, 16);
    sum += __shfl_xor(sum, 32);
    float inv = 1.0f / sum;
    int q = ni * 16 + (lane & 15);
#pragma unroll
    for (int mi = 0; mi < 4; ++mi)
#pragma unroll
      for (int r = 0; r < 4; ++r){
        int kp = mi * 16 + ((lane >> 4) * 4) + r;
        int bo = (q * 128 + kp * 2) ^ ((q & 7) << 4);
        sP[bo >> 1] = f2bf(pv[mi][r] * inv);
      }
  }

  // O = P * V   (A = P rows q, B from V^T rows d) -> D[q][d]
  f32x4 o[4][2] = {};
#pragma unroll
  for (int kc = 0; kc < 2; ++kc){
    short8 pa[4], vb[2];
#pragma unroll
    for (int mtp = 0; mtp < 4; ++mtp){
      int row = mtp * 16 + (lane & 15);
      int bo = (row * 128 + kc * 64 + (lane >> 4) * 16) ^ ((row & 7) << 4);
      pa[mtp] = *(const short8*)(sP + (bo >> 1));
    }
#pragma unroll
    for (int ntp = 0; ntp < 2; ++ntp){
      int row = ntp * 16 + (lane & 15);
      int bo = (row * 128 + kc * 64 + (lane >> 4) * 16) ^ ((row & 7) << 4);
      vb[ntp] = *(const short8*)(sVT + (bo >> 1));
    }
#pragma unroll
    for (int mtp = 0; mtp < 4; ++mtp)
#pragma unroll
      for (int ntp = 0; ntp < 2; ++ntp)
        o[mtp][ntp] = MFMA16(pa[mtp], vb[ntp], o[mtp][ntp]);
  }

#pragma unroll
  for (int mtp = 0; mtp < 4; ++mtp)
#pragma unroll
    for (int r = 0; r < 4; ++r){
      int q = mtp * 16 + (lane >> 4) * 4 + r;
      if (q < 49){
        size_t obase = pxaddr(q) * 256 + h * 32 + (lane & 15);
        attnT[obase]      = f2bf(o[mtp][0][r]);
        attnT[obase + 16] = f2bf(o[mtp][1][r]);
      }
    }
}

// ---------------- GEMM: y[b][o][p] = x[b][o][p] + sum_c Wo[o][c]*attnT[b][p][c] ----------------
__global__ __launch_bounds__(256) void k_gemm_out(const unsigned short* __restrict__ Wob,
                                                  const unsigned short* __restrict__ attnT,
                                                  const float* __restrict__ x,
                                                  float* __restrict__ y){
  int bid = blockIdx.x;
  int mt = bid & 1; int rest = bid >> 1;
  int nt = rest % 392; int b = rest / 392;
  const unsigned short* Asrc = Wob + mt * 128 * 256;
  const unsigned short* Bsrc = attnT + ((size_t)b * HW_ + (size_t)nt * 128) * 256;

  __shared__ unsigned short lds[16384];
  unsigned short* Alds = lds;
  unsigned short* Blds = lds + 8192;

  int tid = threadIdx.x;
  int lane = tid & 63;
  int wave = tid >> 6;
  int wm = wave >> 1, wn = wave & 1;

  f32x4 acc[4][4] = {};

  for (int k0 = 0; k0 < 256; k0 += 64){
    short8 ra[4], rb[4];
#pragma unroll
    for (int c = 0; c < 4; ++c){
      int q = c * 256 + tid;
      int r = q >> 3, sl = q & 7;
      ra[c] = *(const short8*)(Asrc + r * 256 + k0 + sl * 8);
      rb[c] = *(const short8*)(Bsrc + r * 256 + k0 + sl * 8);
    }
    __syncthreads();
#pragma unroll
    for (int c = 0; c < 4; ++c){
      int q = c * 256 + tid;
      int r = q >> 3, sl = q & 7;
      int ps = sl ^ (r & 7);
      *(short8*)(Alds + r * 64 + ps * 8) = ra[c];
      *(short8*)(Blds + r * 64 + ps * 8) = rb[c];
    }
    __syncthreads();
#pragma unroll
    for (int kk = 0; kk < 2; ++kk){
      short8 af[4], bfv[4];
#pragma unroll
      for (int i = 0; i < 4; ++i){
        int row = wm * 64 + i * 16 + (lane & 15);
        int ps = (kk * 4 + (lane >> 4)) ^ (row & 7);
        af[i] = *(const short8*)(Alds + row * 64 + ps * 8);
      }
#pragma unroll
      for (int j = 0; j < 4; ++j){
        int row = wn * 64 + j * 16 + (lane & 15);
        int ps = (kk * 4 + (lane >> 4)) ^ (row & 7);
        bfv[j] = *(const short8*)(Blds + row * 64 + ps * 8);
      }
#pragma unroll
      for (int i = 0; i < 4; ++i)
#pragma unroll
        for (int j = 0; j < 4; ++j)
          acc[i][j] = MFMA16(af[i], bfv[j], acc[i][j]);
    }
  }
  // epilogue: residual add, fp32 store (C,HW layout, coalesced)
#pragma unroll
  for (int i = 0; i < 4; ++i)
#pragma unroll
    for (int j = 0; j < 4; ++j){
      int o = mt*128 + wm*64 + i*16 + (lane>>4)*4;
      int p = nt*128 + wn*64 + j*16 + (lane&15);
      size_t base = ((size_t)(b*256 + o)) * HW_ + p;
#pragma unroll
      for (int r2 = 0; r2 < 4; ++r2){
        float v = acc[i][j][r2] + x[base + (size_t)r2 * HW_];
        y[base + (size_t)r2 * HW_] = v;
      }
    }
}

// ---------------- BN stats over (B,H,W) per channel ----------------
__global__ __launch_bounds__(256) void k_stats(const float* __restrict__ y, float* __restrict__ stats){
  int c = blockIdx.x, t = threadIdx.x;
  float s = 0.f, s2 = 0.f;
  for (int b = 0; b < 4; ++b){
    const float* p = y + ((size_t)(b * 256 + c)) * HW_;
    for (int i = t * 4; i < HW_; i += 1024){
      float4 v = *(const float4*)(p + i);
      s  += v.x + v.y + v.z + v.w;
      s2 += v.x*v.x + v.y*v.y + v.z*v.z + v.w*v.w;
    }
  }
  __shared__ float r1[256], r2[256];
  r1[t] = s; r2[t] = s2; __syncthreads();
  for (int off = 128; off > 0; off >>= 1){
    if (t < off){ r1[t] += r1[t+off]; r2[t] += r2[t+off]; }
    __syncthreads();
  }
  if (t == 0){
    float mean = r1[0] * (1.f / 200704.f);
    float var  = r2[0] * (1.f / 200704.f) - mean * mean;
    stats[c] = mean;
    stats[256 + c] = rsqrtf(var + 1e-5f);
  }
}

// ---------------- in-place normalize ----------------
__global__ __launch_bounds__(256) void k_norm(float* __restrict__ y, const float* __restrict__ stats,
                                              const float* __restrict__ gamma, const float* __restrict__ beta){
  const long long total = 12845056LL;  // 51380224 / 4
  for (long long idx = (long long)blockIdx.x * 256 + threadIdx.x; idx < total; idx += (long long)gridDim.x * 256){
    int c = (int)((idx / 12544) & 255);
    float sc = stats[256 + c] * gamma[c];
    float sh = beta[c] - stats[c] * sc;
    float4* p = (float4*)y + idx;
    float4 v = *p;
    v.x = v.x * sc + sh; v.y = v.y * sc + sh; v.z = v.z * sc + sh; v.w = v.w * sc + sh;
    *p = v;
  }
}

extern "C" void kernel_launch(void* const* d_in, const int* in_sizes, int n_in,
                              void* d_out, int out_size, void* d_ws, size_t ws_size,
                              hipStream_t stream){
  const float* x     = (const float*)d_in[0];
  const float* Wq    = (const float*)d_in[1];
  const float* Wk    = (const float*)d_in[2];
  const float* Wv    = (const float*)d_in[3];
  const float* Wo    = (const float*)d_in[4];
  const float* gamma = (const float*)d_in[5];
  const float* beta  = (const float*)d_in[6];
  float* out = (float*)d_out;

  char* ws = (char*)d_ws;
  unsigned short* Wqkv_b = (unsigned short*)ws;                               // 393216 B
  unsigned short* Wo_b   = (unsigned short*)(ws + 393216);                    // 131072 B
  float*          stats  = (float*)(ws + 524288);                             // 2048 B
  unsigned short* xbT    = (unsigned short*)(ws + 1048576);                   // 102760448 B
  unsigned short* qkvT   = (unsigned short*)(ws + 1048576 + 102760448);       // 308281344 B
  unsigned short* attnT  = xbT;  // alias: xbT dead after k_gemm_qkv (stream-ordered)

  k_convw<<<256, 256, 0, stream>>>(Wq, Wk, Wv, Wo, Wqkv_b, Wo_b);
  k_xpose<<<4 * 4 * 784, 256, 0, stream>>>(x, xbT);
  k_gemm_qkv<<<6 * 392 * 4, 256, 0, stream>>>(Wqkv_b, xbT, qkvT);
  k_attn<<<32768, 64, 0, stream>>>(qkvT, attnT);
  k_gemm_out<<<2 * 392 * 4, 256, 0, stream>>>(Wo_b, attnT, x, out);
  k_stats<<<256, 256, 0, stream>>>(out, stats);
  k_norm<<<4096, 256, 0, stream>>>(out, stats, gamma, beta);
}